// Round 1
// baseline (225.383 us; speedup 1.0000x reference)
//
#include <hip/hip_runtime.h>
#include <math.h>

#define EPSF 1e-5f

// B=256, C=3, H=W=64 (HW=4096), G=128
// ws layout (float offsets)
constexpr int OFF_RED1 = 0;                       // 96*2   bn1 partials (sum,sumsq)
constexpr int OFF_A1B1 = 192;                     // 6      folded bn1 affine a[3],b[3]
constexpr int OFF_RED2 = 256;                     // 128*9  t-moment partials
constexpr int OFF_WTIL = 1536;                    // 128*3  bn2-folded conv1 weights
constexpr int OFF_BTIL = 1920;                    // 128    bn2-folded conv1 bias
constexpr int OFF_F    = 2048;                    // 256*128*9 boundary features
constexpr int OFF_W2E  = OFF_F + 256 * 128 * 9;   // 128*128*9 effective conv2 weights
constexpr int OFF_M    = OFF_W2E + 128 * 128 * 9; // 256*128  pooled conv2 output
constexpr int OFF_X3   = OFF_M + 256 * 128;       // 256*128  relu(bn3(m))
// total = 509952 floats ~= 2.0 MB

__device__ __forceinline__ float wave_sum(float v) {
    #pragma unroll
    for (int off = 32; off > 0; off >>= 1) v += __shfl_down(v, off);
    return v;
}

// ---------- K1: per-channel sum / sumsq of world_state ----------
__global__ __launch_bounds__(256) void k_bn1_stats(const float* __restrict__ x,
                                                   float* __restrict__ red) {
    int bid = blockIdx.x;          // 96 blocks: c = bid%3, seg = bid/3 (8 b's each)
    int c = bid % 3, seg = bid / 3;
    int tid = threadIdx.x;
    float s = 0.f, s2 = 0.f;
    for (int bb = 0; bb < 8; ++bb) {
        int b = seg * 8 + bb;
        const float4* p = (const float4*)(x + (size_t)(b * 3 + c) * 4096);
        for (int i = tid; i < 1024; i += 256) {
            float4 v = p[i];
            s += v.x + v.y + v.z + v.w;
            s2 = fmaf(v.x, v.x, s2); s2 = fmaf(v.y, v.y, s2);
            s2 = fmaf(v.z, v.z, s2); s2 = fmaf(v.w, v.w, s2);
        }
    }
    __shared__ float ls[4], ls2[4];
    float ws_ = wave_sum(s), ws2_ = wave_sum(s2);
    if ((tid & 63) == 0) { ls[tid >> 6] = ws_; ls2[tid >> 6] = ws2_; }
    __syncthreads();
    if (tid == 0) {
        red[bid * 2 + 0] = ls[0] + ls[1] + ls[2] + ls[3];
        red[bid * 2 + 1] = ls2[0] + ls2[1] + ls2[2] + ls2[3];
    }
}

// ---------- K1b: finalize bn1 -> folded affine a1,b1 ----------
__global__ __launch_bounds__(64) void k_bn1_fin(const float* __restrict__ red,
                                                const float* __restrict__ g1,
                                                const float* __restrict__ b1,
                                                float* __restrict__ a1b1) {
    int c = threadIdx.x;
    if (c < 3) {
        float s = 0.f, s2 = 0.f;
        for (int seg = 0; seg < 32; ++seg) {
            s  += red[(seg * 3 + c) * 2 + 0];
            s2 += red[(seg * 3 + c) * 2 + 1];
        }
        float n = 256.f * 4096.f;
        float mean = s / n, var = s2 / n - mean * mean;
        float a = g1[c] * rsqrtf(var + EPSF);
        a1b1[c] = a;
        a1b1[3 + c] = b1[c] - mean * a;
    }
}

// ---------- K2: 3x3 second moments + mean of t = relu(bn1(x)) ----------
__global__ __launch_bounds__(256) void k_t_moments(const float* __restrict__ x,
                                                   const float* __restrict__ a1b1,
                                                   float* __restrict__ red) {
    int bid = blockIdx.x, tid = threadIdx.x;  // 128 blocks x 2 b's
    float A0 = a1b1[0], A1 = a1b1[1], A2 = a1b1[2];
    float B0 = a1b1[3], B1 = a1b1[4], B2 = a1b1[5];
    float acc[9] = {0, 0, 0, 0, 0, 0, 0, 0, 0};
    for (int bb = 0; bb < 2; ++bb) {
        int b = bid * 2 + bb;
        const float4* p0 = (const float4*)(x + (size_t)(b * 3 + 0) * 4096);
        const float4* p1 = (const float4*)(x + (size_t)(b * 3 + 1) * 4096);
        const float4* p2 = (const float4*)(x + (size_t)(b * 3 + 2) * 4096);
        for (int i = tid; i < 1024; i += 256) {
            float4 v0 = p0[i], v1 = p1[i], v2 = p2[i];
            #define MOM(e) { \
                float t0 = fmaxf(0.f, fmaf(A0, v0.e, B0)); \
                float t1 = fmaxf(0.f, fmaf(A1, v1.e, B1)); \
                float t2 = fmaxf(0.f, fmaf(A2, v2.e, B2)); \
                acc[0] += t0; acc[1] += t1; acc[2] += t2; \
                acc[3] = fmaf(t0, t0, acc[3]); acc[4] = fmaf(t0, t1, acc[4]); \
                acc[5] = fmaf(t0, t2, acc[5]); acc[6] = fmaf(t1, t1, acc[6]); \
                acc[7] = fmaf(t1, t2, acc[7]); acc[8] = fmaf(t2, t2, acc[8]); }
            MOM(x) MOM(y) MOM(z) MOM(w)
            #undef MOM
        }
    }
    __shared__ float lw[4][9];
    #pragma unroll
    for (int k = 0; k < 9; ++k) {
        float v = wave_sum(acc[k]);
        if ((tid & 63) == 0) lw[tid >> 6][k] = v;
    }
    __syncthreads();
    if (tid == 0) {
        #pragma unroll
        for (int k = 0; k < 9; ++k)
            red[bid * 9 + k] = lw[0][k] + lw[1][k] + lw[2][k] + lw[3][k];
    }
}

// ---------- K2b: analytic bn2 from moments; fold into conv1 weights ----------
__global__ __launch_bounds__(128) void k_bn2_fin(const float* __restrict__ red,
                                                 const float* __restrict__ w1,
                                                 const float* __restrict__ g2,
                                                 const float* __restrict__ b2,
                                                 float* __restrict__ wtil,
                                                 float* __restrict__ btil) {
    __shared__ float mom[9];  // mu0,mu1,mu2, m00,m01,m02,m11,m12,m22 (E[.])
    int tid = threadIdx.x;
    if (tid < 9) {
        float s = 0.f;
        for (int i = 0; i < 128; ++i) s += red[i * 9 + tid];
        mom[tid] = s / (256.f * 4096.f);
    }
    __syncthreads();
    int g = tid;
    float wa = w1[g * 3 + 0], wb = w1[g * 3 + 1], wc = w1[g * 3 + 2];
    float mean = wa * mom[0] + wb * mom[1] + wc * mom[2];
    float ey2 = wa * wa * mom[3] + wb * wb * mom[6] + wc * wc * mom[8]
              + 2.f * (wa * wb * mom[4] + wa * wc * mom[5] + wb * wc * mom[7]);
    float var = ey2 - mean * mean;
    float a = g2[g] * rsqrtf(var + EPSF);
    float bb = b2[g] - mean * a;
    wtil[g * 3 + 0] = a * wa;
    wtil[g * 3 + 1] = a * wb;
    wtil[g * 3 + 2] = a * wc;
    btil[g] = bb;
}

// ---------- K4a: effective conv2 weights (9 boundary-feature coeffs) ----------
// feature order: S, R0, R63, C0, C63, u00, u0_63, u63_0, u63_63
__global__ __launch_bounds__(256) void k_w2eff(const float* __restrict__ w2,
                                               float* __restrict__ w2e) {
    int idx = blockIdx.x * 256 + threadIdx.x;  // 64 blocks -> 16384 (g,g') pairs
    int g = idx >> 7, gp = idx & 127;
    const float* wp = w2 + (size_t)(g * 128 + gp) * 9;  // [ky][kx]
    float v0 = wp[0], v1 = wp[1], v2 = wp[2], v3 = wp[3], v4 = wp[4],
          v5 = wp[5], v6 = wp[6], v7 = wp[7], v8 = wp[8];
    float c[9];
    c[0] = ((v0 + v1) + (v2 + v3)) + ((v4 + v5) + (v6 + v7)) + v8;
    c[1] = -(v6 + v7 + v8);   // row 0 excluded when ky==2
    c[2] = -(v0 + v1 + v2);   // row 63 excluded when ky==0
    c[3] = -(v2 + v5 + v8);   // col 0 excluded when kx==2
    c[4] = -(v0 + v3 + v6);   // col 63 excluded when kx==0
    c[5] = v8;                // u[0,0]   re-add (ky==2,kx==2)
    c[6] = v6;                // u[0,63]  (ky==2,kx==0)
    c[7] = v2;                // u[63,0]  (ky==0,kx==2)
    c[8] = v0;                // u[63,63] (ky==0,kx==0)
    #pragma unroll
    for (int k = 0; k < 9; ++k) {
        int jj = gp * 9 + k;                       // 0..1151
        w2e[(size_t)(jj >> 2) * 512 + g * 4 + (jj & 3)] = c[k];  // [jblk][g][4]
    }
}

// ---------- K3: the heavy kernel — boundary features of u = relu(w~.t + b~) ----------
__global__ __launch_bounds__(512) void k_features(const float* __restrict__ x,
                                                  const float* __restrict__ a1b1,
                                                  const float* __restrict__ wtil,
                                                  const float* __restrict__ btil,
                                                  float* __restrict__ F) {
    __shared__ float lds[12288];  // t planes [c][4096]; reused for reductions
    int b = blockIdx.x, tid = threadIdx.x;
    float A0 = a1b1[0], A1 = a1b1[1], A2 = a1b1[2];
    float B0 = a1b1[3], B1 = a1b1[4], B2 = a1b1[5];
    const float4* xb = (const float4*)(x + (size_t)b * 3 * 4096);
    for (int i = tid; i < 3072; i += 512) {
        float4 v = xb[i];
        int c = i >> 10;
        float a = (c == 0) ? A0 : ((c == 1) ? A1 : A2);
        float bb = (c == 0) ? B0 : ((c == 1) ? B1 : B2);
        v.x = fmaxf(0.f, fmaf(a, v.x, bb));
        v.y = fmaxf(0.f, fmaf(a, v.y, bb));
        v.z = fmaxf(0.f, fmaf(a, v.z, bb));
        v.w = fmaxf(0.f, fmaf(a, v.w, bb));
        *(float4*)&lds[i << 2] = v;
    }
    __syncthreads();
    int gl = tid & 31, q = tid >> 5;  // q 0..15 -> rows 4q..4q+3; 4 g's per thread
    float w0[4], w1v[4], w2v[4], bw[4];
    #pragma unroll
    for (int j = 0; j < 4; ++j) {
        int g = gl + 32 * j;
        w0[j] = wtil[g * 3 + 0]; w1v[j] = wtil[g * 3 + 1];
        w2v[j] = wtil[g * 3 + 2]; bw[j] = btil[g];
    }
    float S[4] = {0, 0, 0, 0}, C0a[4] = {0, 0, 0, 0}, C63a[4] = {0, 0, 0, 0};
    float R0a[4] = {0, 0, 0, 0}, R63a[4] = {0, 0, 0, 0};
    float u00[4] = {0, 0, 0, 0}, u063[4] = {0, 0, 0, 0};
    float u630[4] = {0, 0, 0, 0}, u6363[4] = {0, 0, 0, 0};
    for (int r = q * 4; r < q * 4 + 4; ++r) {
        bool e0 = (r == 0), e63 = (r == 63);
        for (int x4 = 0; x4 < 64; x4 += 4) {
            int pp = r * 64 + x4;
            float4 t0 = *(const float4*)&lds[pp];
            float4 t1 = *(const float4*)&lds[4096 + pp];
            float4 t2 = *(const float4*)&lds[8192 + pp];
            #pragma unroll
            for (int j = 0; j < 4; ++j) {
                float u0 = fmaxf(0.f, fmaf(w0[j], t0.x, fmaf(w1v[j], t1.x, fmaf(w2v[j], t2.x, bw[j]))));
                float u1 = fmaxf(0.f, fmaf(w0[j], t0.y, fmaf(w1v[j], t1.y, fmaf(w2v[j], t2.y, bw[j]))));
                float u2 = fmaxf(0.f, fmaf(w0[j], t0.z, fmaf(w1v[j], t1.z, fmaf(w2v[j], t2.z, bw[j]))));
                float u3 = fmaxf(0.f, fmaf(w0[j], t0.w, fmaf(w1v[j], t1.w, fmaf(w2v[j], t2.w, bw[j]))));
                float s4 = (u0 + u1) + (u2 + u3);
                S[j] += s4;
                if (x4 == 0)  C0a[j] += u0;
                if (x4 == 60) C63a[j] += u3;
                if (e0)  { R0a[j] += s4;  if (x4 == 0) u00[j] = u0;  if (x4 == 60) u063[j] = u3; }
                if (e63) { R63a[j] += s4; if (x4 == 0) u630[j] = u0; if (x4 == 60) u6363[j] = u3; }
            }
        }
    }
    // reduce across q (16 partials per g); two phases to stay within 48KB LDS
    __syncthreads();
    #pragma unroll
    for (int j = 0; j < 4; ++j) {
        int g = gl + 32 * j;
        lds[(0 * 128 + g) * 16 + q] = S[j];
        lds[(1 * 128 + g) * 16 + q] = R0a[j];
        lds[(2 * 128 + g) * 16 + q] = R63a[j];
        lds[(3 * 128 + g) * 16 + q] = C0a[j];
        lds[(4 * 128 + g) * 16 + q] = C63a[j];
    }
    __syncthreads();
    if (tid < 128) {
        float* Fb = F + (size_t)b * 1152 + tid * 9;
        #pragma unroll
        for (int k = 0; k < 5; ++k) {
            float s = 0.f;
            #pragma unroll
            for (int qq = 0; qq < 16; ++qq) s += lds[(k * 128 + tid) * 16 + qq];
            Fb[k] = s;
        }
    }
    __syncthreads();
    #pragma unroll
    for (int j = 0; j < 4; ++j) {
        int g = gl + 32 * j;
        lds[(0 * 128 + g) * 16 + q] = u00[j];
        lds[(1 * 128 + g) * 16 + q] = u063[j];
        lds[(2 * 128 + g) * 16 + q] = u630[j];
        lds[(3 * 128 + g) * 16 + q] = u6363[j];
    }
    __syncthreads();
    if (tid < 128) {
        float* Fb = F + (size_t)b * 1152 + tid * 9;
        #pragma unroll
        for (int k = 0; k < 4; ++k) {
            float s = 0.f;
            #pragma unroll
            for (int qq = 0; qq < 16; ++qq) s += lds[(k * 128 + tid) * 16 + qq];
            Fb[5 + k] = s;
        }
    }
}

// ---------- K4: m[b,g] = (1/4096) * sum_j w2e[j][g] * F[b][j] ----------
__global__ __launch_bounds__(256) void k_contract(const float* __restrict__ F,
                                                  const float* __restrict__ w2e,
                                                  float* __restrict__ m) {
    __shared__ float Fl[1152];
    __shared__ float part[128];
    int b = blockIdx.x, tid = threadIdx.x;
    int g = tid & 127, half = tid >> 7;
    for (int i = tid; i < 1152; i += 256) Fl[i] = F[(size_t)b * 1152 + i];
    __syncthreads();
    float acc = 0.f;
    int jb0 = half * 144;
    #pragma unroll 4
    for (int t = 0; t < 144; ++t) {
        int jb = jb0 + t;
        float4 wv = *(const float4*)&w2e[(size_t)jb * 512 + g * 4];
        float4 fv = *(const float4*)&Fl[jb * 4];
        acc = fmaf(wv.x, fv.x, fmaf(wv.y, fv.y, fmaf(wv.z, fv.z, fmaf(wv.w, fv.w, acc))));
    }
    if (half == 1) part[g] = acc;
    __syncthreads();
    if (half == 0) m[b * 128 + g] = (acc + part[g]) * (1.f / 4096.f);
}

// ---------- K5: bn3 over batch + relu ----------
__global__ __launch_bounds__(64) void k_bn3(const float* __restrict__ m,
                                            const float* __restrict__ g3,
                                            const float* __restrict__ b3,
                                            float* __restrict__ x3) {
    int g = blockIdx.x, l = threadIdx.x;
    float v[4]; float s = 0.f, s2 = 0.f;
    #pragma unroll
    for (int i = 0; i < 4; ++i) {
        v[i] = m[(l * 4 + i) * 128 + g];
        s += v[i]; s2 = fmaf(v[i], v[i], s2);
    }
    s = wave_sum(s); s2 = wave_sum(s2);
    s = __shfl(s, 0); s2 = __shfl(s2, 0);
    float mean = s / 256.f, var = s2 / 256.f - mean * mean;
    float a = g3[g] * rsqrtf(var + EPSF);
    float bb = b3[g] - mean * a;
    #pragma unroll
    for (int i = 0; i < 4; ++i) x3[(l * 4 + i) * 128 + g] = fmaxf(0.f, fmaf(a, v[i], bb));
}

// ---------- K6: all the small heads, one wave per batch row ----------
__global__ __launch_bounds__(64) void k_head(
    const float* __restrict__ agent, const float* __restrict__ action,
    const float* __restrict__ x3,
    const float* __restrict__ fc1w, const float* __restrict__ fc1b,
    const float* __restrict__ lnmig, const float* __restrict__ lnmib,
    const float* __restrict__ miw1, const float* __restrict__ miw2,
    const float* __restrict__ embc, const float* __restrict__ embe,
    const float* __restrict__ embnc, const float* __restrict__ embns,
    const float* __restrict__ embp,
    const float* __restrict__ lncag, const float* __restrict__ lncab,
    const float* __restrict__ caw1, const float* __restrict__ cab1,
    const float* __restrict__ caw2, const float* __restrict__ cab2,
    const float* __restrict__ lncg, const float* __restrict__ lncb,
    const float* __restrict__ cw,
    const float* __restrict__ lndg, const float* __restrict__ lndb,
    const float* __restrict__ dw1, const float* __restrict__ dw2,
    float* __restrict__ out) {
    int b = blockIdx.x, l = threadIdx.x;
    __shared__ float as[28], lnv[28], h1[100], y20[20], lnca[24], h2[100],
                     z20[20], cat[60], lnsc[56], h3[50];
    // ---- agent LN (28) ----
    float av = (l < 28) ? agent[b * 28 + l] : 0.f;
    if (l < 28) as[l] = av;
    float asum = wave_sum(av);
    float asq = wave_sum(av * av);
    asum = __shfl(asum, 0); asq = __shfl(asq, 0);
    {
        float mean = asum / 28.f, var = asq / 28.f - mean * mean;
        float rs = rsqrtf(var + EPSF);
        if (l < 28) lnv[l] = (av - mean) * rs * lnmig[l] + lnmib[l];
    }
    __syncthreads();
    // ---- mi mlp: 100 <- 28, then 20 <- 100 ----
    for (int j = l; j < 100; j += 64) {
        float a = 0.f;
        for (int i = 0; i < 28; ++i) a = fmaf(miw1[j * 28 + i], lnv[i], a);
        h1[j] = fmaxf(0.f, a);
    }
    __syncthreads();
    if (l < 20) {
        float a = 0.f;
        for (int i = 0; i < 100; ++i) a = fmaf(miw2[l * 100 + i], h1[i], a);
        y20[l] = fmaxf(0.f, a);
    }
    // ---- build acts[24] ----
    const float* ab = action + b * 15;
    float actv = 0.f;
    if (l < 24) {
        if (l < 4)       actv = ab[l];
        else if (l < 7)  { int ix = (int)ab[4];  actv = embc[ix * 3 + (l - 4)]; }
        else if (l < 10) { int ix = (int)ab[5];  actv = embe[ix * 3 + (l - 7)]; }
        else if (l < 13) actv = ab[l - 4];
        else if (l < 16) { int ix = (int)ab[9];  actv = embnc[ix * 3 + (l - 13)]; }
        else if (l < 18) { int ix = (int)ab[10]; actv = embns[ix * 2 + (l - 16)]; }
        else if (l < 21) { int ix = (int)ab[11]; actv = embp[ix * 3 + (l - 18)]; }
        else             actv = ab[l - 9];
    }
    float cs = wave_sum(actv), cs2 = wave_sum(actv * actv);
    cs = __shfl(cs, 0); cs2 = __shfl(cs2, 0);
    {
        float mean = cs / 24.f, var = cs2 / 24.f - mean * mean;
        float rs = rsqrtf(var + EPSF);
        if (l < 24) lnca[l] = (actv - mean) * rs * lncag[l] + lncab[l];
    }
    __syncthreads();
    // ---- ca mlp ----
    for (int j = l; j < 100; j += 64) {
        float a = cab1[j];
        for (int i = 0; i < 24; ++i) a = fmaf(caw1[j * 24 + i], lnca[i], a);
        h2[j] = fmaxf(0.f, a);
    }
    __syncthreads();
    if (l < 20) {
        float a = cab2[l];
        for (int i = 0; i < 100; ++i) a = fmaf(caw2[l * 100 + i], h2[i], a);
        z20[l] = fmaxf(0.f, a);
    }
    // ---- cnn fc1 ----
    if (l < 20) {
        float a = fc1b[l];
        const float* xbp = x3 + b * 128;
        for (int i = 0; i < 128; ++i) a = fmaf(fc1w[l * 128 + i], xbp[i], a);
        cat[l] = fmaxf(0.f, a);
    }
    __syncthreads();
    if (l < 20) { cat[20 + l] = y20[l]; cat[40 + l] = z20[l]; }
    __syncthreads();
    // ---- combined head: LN(60) -> dot -> tanh ----
    float cv = (l < 60) ? cat[l] : 0.f;
    float ss = wave_sum(cv), ss2 = wave_sum(cv * cv);
    ss = __shfl(ss, 0); ss2 = __shfl(ss2, 0);
    float mean60 = ss / 60.f, var60 = ss2 / 60.f - mean60 * mean60;
    float rs60 = rsqrtf(var60 + EPSF);
    float term = (l < 60) ? cw[l] * ((cv - mean60) * rs60 * lncg[l] + lncb[l]) : 0.f;
    term = wave_sum(term);
    if (l == 0) out[b] = tanhf(term);
    // ---- dist net: sc = [zeros(28), agent] ----
    float mean56 = asum / 56.f, var56 = asq / 56.f - mean56 * mean56;
    float rs56 = rsqrtf(var56 + EPSF);
    if (l < 56) {
        float vv = (l < 28) ? 0.f : as[l - 28];
        lnsc[l] = (vv - mean56) * rs56 * lndg[l] + lndb[l];
    }
    __syncthreads();
    if (l < 50) {
        float a = 0.f;
        for (int i = 0; i < 56; ++i) a = fmaf(dw1[l * 56 + i], lnsc[i], a);
        h3[l] = tanhf(a);
    }
    __syncthreads();
    float dterm = (l < 50) ? dw2[l] * h3[l] : 0.f;
    dterm = wave_sum(dterm);
    if (l == 0) out[256 + b] = tanhf(dterm);
}

extern "C" void kernel_launch(void* const* d_in, const int* in_sizes, int n_in,
                              void* d_out, int out_size, void* d_ws, size_t ws_size,
                              hipStream_t stream) {
    (void)in_sizes; (void)n_in; (void)out_size; (void)ws_size;
    const float* agent  = (const float*)d_in[0];
    const float* world  = (const float*)d_in[1];
    const float* action = (const float*)d_in[2];
    const float* bn1_g  = (const float*)d_in[3];
    const float* bn1_b  = (const float*)d_in[4];
    const float* conv1w = (const float*)d_in[5];
    const float* bn2_g  = (const float*)d_in[6];
    const float* bn2_b  = (const float*)d_in[7];
    const float* conv2w = (const float*)d_in[8];
    const float* bn3_g  = (const float*)d_in[9];
    const float* bn3_b  = (const float*)d_in[10];
    const float* fc1w   = (const float*)d_in[11];
    const float* fc1b   = (const float*)d_in[12];
    const float* lnmig  = (const float*)d_in[13];
    const float* lnmib  = (const float*)d_in[14];
    const float* miw1   = (const float*)d_in[15];
    const float* miw2   = (const float*)d_in[16];
    const float* embc   = (const float*)d_in[17];
    const float* embe   = (const float*)d_in[18];
    const float* embnc  = (const float*)d_in[19];
    const float* embns  = (const float*)d_in[20];
    const float* embp   = (const float*)d_in[21];
    const float* lncag  = (const float*)d_in[22];
    const float* lncab  = (const float*)d_in[23];
    const float* caw1   = (const float*)d_in[24];
    const float* cab1   = (const float*)d_in[25];
    const float* caw2   = (const float*)d_in[26];
    const float* cab2   = (const float*)d_in[27];
    const float* lncg   = (const float*)d_in[28];
    const float* lncb   = (const float*)d_in[29];
    const float* cw     = (const float*)d_in[30];
    const float* lndg   = (const float*)d_in[31];
    const float* lndb   = (const float*)d_in[32];
    const float* dw1    = (const float*)d_in[33];
    const float* dw2    = (const float*)d_in[34];
    float* out = (float*)d_out;
    float* ws = (float*)d_ws;

    hipLaunchKernelGGL(k_bn1_stats, dim3(96), dim3(256), 0, stream, world, ws + OFF_RED1);
    hipLaunchKernelGGL(k_bn1_fin, dim3(1), dim3(64), 0, stream,
                       ws + OFF_RED1, bn1_g, bn1_b, ws + OFF_A1B1);
    hipLaunchKernelGGL(k_t_moments, dim3(128), dim3(256), 0, stream,
                       world, ws + OFF_A1B1, ws + OFF_RED2);
    hipLaunchKernelGGL(k_bn2_fin, dim3(1), dim3(128), 0, stream,
                       ws + OFF_RED2, conv1w, bn2_g, bn2_b, ws + OFF_WTIL, ws + OFF_BTIL);
    hipLaunchKernelGGL(k_w2eff, dim3(64), dim3(256), 0, stream, conv2w, ws + OFF_W2E);
    hipLaunchKernelGGL(k_features, dim3(256), dim3(512), 0, stream,
                       world, ws + OFF_A1B1, ws + OFF_WTIL, ws + OFF_BTIL, ws + OFF_F);
    hipLaunchKernelGGL(k_contract, dim3(256), dim3(256), 0, stream,
                       ws + OFF_F, ws + OFF_W2E, ws + OFF_M);
    hipLaunchKernelGGL(k_bn3, dim3(128), dim3(64), 0, stream,
                       ws + OFF_M, bn3_g, bn3_b, ws + OFF_X3);
    hipLaunchKernelGGL(k_head, dim3(256), dim3(64), 0, stream,
                       agent, action, ws + OFF_X3, fc1w, fc1b,
                       lnmig, lnmib, miw1, miw2,
                       embc, embe, embnc, embns, embp,
                       lncag, lncab, caw1, cab1, caw2, cab2,
                       lncg, lncb, cw, lndg, lndb, dw1, dw2, out);
}

// Round 2
// 199.854 us; speedup vs baseline: 1.1277x; 1.1277x over previous
//
#include <hip/hip_runtime.h>
#include <math.h>

#define EPSF 1e-5f

// B=256, C=3, H=W=64 (HW=4096), G=128
// ws layout (float offsets)
constexpr int OFF_RED1 = 0;        // 192*2  bn1 partials (sum,sumsq)
constexpr int OFF_A1B1 = 384;      // 6      folded bn1 affine a[3],b[3] (written by kB blk0)
constexpr int OFF_RED2 = 512;      // 256*9  t-moment partials
constexpr int OFF_W2E  = 4096;     // 128*128*9 effective conv2 weights
constexpr int OFF_M    = OFF_W2E + 128 * 128 * 9;  // 256*128 pooled conv2 output

__device__ __forceinline__ float wave_sum(float v) {
    #pragma unroll
    for (int off = 32; off > 0; off >>= 1) v += __shfl_down(v, off);
    return v;
}

// ---------- kA: bn1 partial stats (blocks 0..191) + effective conv2 weights (192..255) ----------
__global__ __launch_bounds__(256) void kA(const float* __restrict__ x,
                                          const float* __restrict__ w2,
                                          float* __restrict__ red1,
                                          float* __restrict__ w2e) {
    int blk = blockIdx.x, tid = threadIdx.x;
    if (blk < 192) {
        int c = blk % 3, seg = blk / 3;  // 64 segs x 4 b
        float s = 0.f, s2 = 0.f;
        for (int bb = 0; bb < 4; ++bb) {
            int b = seg * 4 + bb;
            const float4* p = (const float4*)(x + (size_t)(b * 3 + c) * 4096);
            for (int i = tid; i < 1024; i += 256) {
                float4 v = p[i];
                s += v.x + v.y + v.z + v.w;
                s2 = fmaf(v.x, v.x, s2); s2 = fmaf(v.y, v.y, s2);
                s2 = fmaf(v.z, v.z, s2); s2 = fmaf(v.w, v.w, s2);
            }
        }
        __shared__ float ls[4], ls2[4];
        float ws_ = wave_sum(s), ws2_ = wave_sum(s2);
        if ((tid & 63) == 0) { ls[tid >> 6] = ws_; ls2[tid >> 6] = ws2_; }
        __syncthreads();
        if (tid == 0) {
            red1[blk * 2 + 0] = ls[0] + ls[1] + ls[2] + ls[3];
            red1[blk * 2 + 1] = ls2[0] + ls2[1] + ls2[2] + ls2[3];
        }
    } else {
        // effective conv2 weights: feature order S,R0,R63,C0,C63,u00,u0_63,u63_0,u63_63
        int idx = (blk - 192) * 256 + tid;  // 16384 (g,g') pairs
        int g = idx >> 7, gp = idx & 127;
        const float* wp = w2 + (size_t)(g * 128 + gp) * 9;  // [ky][kx]
        float v0 = wp[0], v1 = wp[1], v2 = wp[2], v3 = wp[3], v4 = wp[4],
              v5 = wp[5], v6 = wp[6], v7 = wp[7], v8 = wp[8];
        float c[9];
        c[0] = ((v0 + v1) + (v2 + v3)) + ((v4 + v5) + (v6 + v7)) + v8;
        c[1] = -(v6 + v7 + v8);
        c[2] = -(v0 + v1 + v2);
        c[3] = -(v2 + v5 + v8);
        c[4] = -(v0 + v3 + v6);
        c[5] = v8; c[6] = v6; c[7] = v2; c[8] = v0;
        #pragma unroll
        for (int k = 0; k < 9; ++k) {
            int jj = gp * 9 + k;                                     // 0..1151
            w2e[(size_t)(jj >> 2) * 512 + g * 4 + (jj & 3)] = c[k];  // [jblk][g][4]
        }
    }
}

// ---------- kB: in-block bn1 finalize + per-b 3x3 second moments of t = relu(bn1(x)) ----------
__global__ __launch_bounds__(256) void kB(const float* __restrict__ x,
                                          const float* __restrict__ red1,
                                          const float* __restrict__ g1,
                                          const float* __restrict__ b1,
                                          float* __restrict__ red2,
                                          float* __restrict__ a1b1) {
    __shared__ float ab[6];
    int b = blockIdx.x, tid = threadIdx.x;
    if (tid < 3) {
        float s = 0.f, s2 = 0.f;
        for (int seg = 0; seg < 64; ++seg) {
            s  += red1[(seg * 3 + tid) * 2 + 0];
            s2 += red1[(seg * 3 + tid) * 2 + 1];
        }
        float n = 256.f * 4096.f;
        float mean = s / n, var = s2 / n - mean * mean;
        float a = g1[tid] * rsqrtf(var + EPSF);
        ab[tid] = a; ab[3 + tid] = b1[tid] - mean * a;
        if (b == 0) { a1b1[tid] = a; a1b1[3 + tid] = ab[3 + tid]; }
    }
    __syncthreads();
    float A0 = ab[0], A1 = ab[1], A2 = ab[2];
    float B0 = ab[3], B1 = ab[4], B2 = ab[5];
    float acc[9] = {0, 0, 0, 0, 0, 0, 0, 0, 0};
    const float4* p0 = (const float4*)(x + (size_t)(b * 3 + 0) * 4096);
    const float4* p1 = (const float4*)(x + (size_t)(b * 3 + 1) * 4096);
    const float4* p2 = (const float4*)(x + (size_t)(b * 3 + 2) * 4096);
    for (int i = tid; i < 1024; i += 256) {
        float4 v0 = p0[i], v1 = p1[i], v2 = p2[i];
        #define MOM(e) { \
            float t0 = fmaxf(0.f, fmaf(A0, v0.e, B0)); \
            float t1 = fmaxf(0.f, fmaf(A1, v1.e, B1)); \
            float t2 = fmaxf(0.f, fmaf(A2, v2.e, B2)); \
            acc[0] += t0; acc[1] += t1; acc[2] += t2; \
            acc[3] = fmaf(t0, t0, acc[3]); acc[4] = fmaf(t0, t1, acc[4]); \
            acc[5] = fmaf(t0, t2, acc[5]); acc[6] = fmaf(t1, t1, acc[6]); \
            acc[7] = fmaf(t1, t2, acc[7]); acc[8] = fmaf(t2, t2, acc[8]); }
        MOM(x) MOM(y) MOM(z) MOM(w)
        #undef MOM
    }
    __shared__ float lw[4][9];
    #pragma unroll
    for (int k = 0; k < 9; ++k) {
        float v = wave_sum(acc[k]);
        if ((tid & 63) == 0) lw[tid >> 6][k] = v;
    }
    __syncthreads();
    if (tid == 0) {
        #pragma unroll
        for (int k = 0; k < 9; ++k)
            red2[b * 9 + k] = lw[0][k] + lw[1][k] + lw[2][k] + lw[3][k];
    }
}

// ---------- kC: bn2 fold (redundant per block) + boundary features + contract -> m[b,:] ----------
__global__ __launch_bounds__(512) void kC(const float* __restrict__ x,
                                          const float* __restrict__ red2,
                                          const float* __restrict__ w1,
                                          const float* __restrict__ g2,
                                          const float* __restrict__ b2,
                                          const float* __restrict__ a1b1,
                                          const float* __restrict__ w2e,
                                          float* __restrict__ m) {
    __shared__ __align__(16) float lds[12288];  // t planes; reused for reductions + contract
    __shared__ __align__(16) float Fsh[1152];
    __shared__ float wt[384], bt[128], momp[288], mom[9], ab[6];
    int b = blockIdx.x, tid = threadIdx.x;
    if (tid < 6) ab[tid] = a1b1[tid];
    if (tid < 288) {  // 32 segs x 9 moments, 8 rows each
        int seg = tid / 9, k = tid - seg * 9;
        float s = 0.f;
        for (int r = 0; r < 8; ++r) s += red2[(seg * 8 + r) * 9 + k];
        momp[tid] = s;
    }
    __syncthreads();
    if (tid < 9) {
        float s = 0.f;
        for (int sg = 0; sg < 32; ++sg) s += momp[sg * 9 + tid];
        mom[tid] = s / (256.f * 4096.f);
    }
    // stage t planes (ab is ready — barrier above)
    {
        float A0 = ab[0], A1 = ab[1], A2 = ab[2];
        float B0 = ab[3], B1 = ab[4], B2 = ab[5];
        const float4* xb = (const float4*)(x + (size_t)b * 3 * 4096);
        for (int i = tid; i < 3072; i += 512) {
            float4 v = xb[i];
            int c = i >> 10;
            float a = (c == 0) ? A0 : ((c == 1) ? A1 : A2);
            float bb = (c == 0) ? B0 : ((c == 1) ? B1 : B2);
            v.x = fmaxf(0.f, fmaf(a, v.x, bb));
            v.y = fmaxf(0.f, fmaf(a, v.y, bb));
            v.z = fmaxf(0.f, fmaf(a, v.z, bb));
            v.w = fmaxf(0.f, fmaf(a, v.w, bb));
            *(float4*)&lds[i << 2] = v;
        }
    }
    __syncthreads();
    if (tid < 128) {  // bn2 fold into conv1 weights
        int g = tid;
        float wa = w1[g * 3 + 0], wb = w1[g * 3 + 1], wc = w1[g * 3 + 2];
        float mean = wa * mom[0] + wb * mom[1] + wc * mom[2];
        float ey2 = wa * wa * mom[3] + wb * wb * mom[6] + wc * wc * mom[8]
                  + 2.f * (wa * wb * mom[4] + wa * wc * mom[5] + wb * wc * mom[7]);
        float var = ey2 - mean * mean;
        float a = g2[g] * rsqrtf(var + EPSF);
        wt[g * 3 + 0] = a * wa; wt[g * 3 + 1] = a * wb; wt[g * 3 + 2] = a * wc;
        bt[g] = b2[g] - mean * a;
    }
    __syncthreads();
    // features
    int gl = tid & 31, q = tid >> 5;  // q 0..15 -> rows 4q..4q+3; 4 g's per thread
    float w0[4], w1v[4], w2v[4], bw[4];
    #pragma unroll
    for (int j = 0; j < 4; ++j) {
        int g = gl + 32 * j;
        w0[j] = wt[g * 3 + 0]; w1v[j] = wt[g * 3 + 1];
        w2v[j] = wt[g * 3 + 2]; bw[j] = bt[g];
    }
    float S[4] = {0, 0, 0, 0}, C0a[4] = {0, 0, 0, 0}, C63a[4] = {0, 0, 0, 0};
    float R0a[4] = {0, 0, 0, 0}, R63a[4] = {0, 0, 0, 0};
    float u00[4] = {0, 0, 0, 0}, u063[4] = {0, 0, 0, 0};
    float u630[4] = {0, 0, 0, 0}, u6363[4] = {0, 0, 0, 0};
    for (int r = q * 4; r < q * 4 + 4; ++r) {
        bool e0 = (r == 0), e63 = (r == 63);
        for (int x4 = 0; x4 < 64; x4 += 4) {
            int pp = r * 64 + x4;
            float4 t0 = *(const float4*)&lds[pp];
            float4 t1 = *(const float4*)&lds[4096 + pp];
            float4 t2 = *(const float4*)&lds[8192 + pp];
            #pragma unroll
            for (int j = 0; j < 4; ++j) {
                float u0 = fmaxf(0.f, fmaf(w0[j], t0.x, fmaf(w1v[j], t1.x, fmaf(w2v[j], t2.x, bw[j]))));
                float u1 = fmaxf(0.f, fmaf(w0[j], t0.y, fmaf(w1v[j], t1.y, fmaf(w2v[j], t2.y, bw[j]))));
                float u2 = fmaxf(0.f, fmaf(w0[j], t0.z, fmaf(w1v[j], t1.z, fmaf(w2v[j], t2.z, bw[j]))));
                float u3 = fmaxf(0.f, fmaf(w0[j], t0.w, fmaf(w1v[j], t1.w, fmaf(w2v[j], t2.w, bw[j]))));
                float s4 = (u0 + u1) + (u2 + u3);
                S[j] += s4;
                if (x4 == 0)  C0a[j] += u0;
                if (x4 == 60) C63a[j] += u3;
                if (e0)  { R0a[j] += s4;  if (x4 == 0) u00[j] = u0;  if (x4 == 60) u063[j] = u3; }
                if (e63) { R63a[j] += s4; if (x4 == 0) u630[j] = u0; if (x4 == 60) u6363[j] = u3; }
            }
        }
    }
    // reduce across q into Fsh (two phases, reusing t-plane lds)
    __syncthreads();
    #pragma unroll
    for (int j = 0; j < 4; ++j) {
        int g = gl + 32 * j;
        lds[(0 * 128 + g) * 16 + q] = S[j];
        lds[(1 * 128 + g) * 16 + q] = R0a[j];
        lds[(2 * 128 + g) * 16 + q] = R63a[j];
        lds[(3 * 128 + g) * 16 + q] = C0a[j];
        lds[(4 * 128 + g) * 16 + q] = C63a[j];
    }
    __syncthreads();
    if (tid < 128) {
        #pragma unroll
        for (int k = 0; k < 5; ++k) {
            float s = 0.f;
            #pragma unroll
            for (int qq = 0; qq < 16; ++qq) s += lds[(k * 128 + tid) * 16 + qq];
            Fsh[tid * 9 + k] = s;
        }
    }
    __syncthreads();
    #pragma unroll
    for (int j = 0; j < 4; ++j) {
        int g = gl + 32 * j;
        lds[(0 * 128 + g) * 16 + q] = u00[j];
        lds[(1 * 128 + g) * 16 + q] = u063[j];
        lds[(2 * 128 + g) * 16 + q] = u630[j];
        lds[(3 * 128 + g) * 16 + q] = u6363[j];
    }
    __syncthreads();
    if (tid < 128) {
        #pragma unroll
        for (int k = 0; k < 4; ++k) {
            float s = 0.f;
            #pragma unroll
            for (int qq = 0; qq < 16; ++qq) s += lds[(k * 128 + tid) * 16 + qq];
            Fsh[tid * 9 + 5 + k] = s;
        }
    }
    __syncthreads();
    // contract: m[b,g] = (1/4096) * sum_j w2e[j][g] * Fsh[j], split over 4 j-chunks
    {
        int chunk = tid >> 7, g = tid & 127;
        float acc = 0.f;
        #pragma unroll 4
        for (int t = 0; t < 72; ++t) {
            int jb = chunk * 72 + t;
            float4 wv = *(const float4*)&w2e[(size_t)jb * 512 + g * 4];
            float4 fv = *(const float4*)&Fsh[jb * 4];
            acc = fmaf(wv.x, fv.x, fmaf(wv.y, fv.y, fmaf(wv.z, fv.z, fmaf(wv.w, fv.w, acc))));
        }
        lds[chunk * 128 + g] = acc;
    }
    __syncthreads();
    if (tid < 128)
        m[b * 128 + tid] = (lds[tid] + lds[128 + tid] + lds[256 + tid] + lds[384 + tid]) * (1.f / 4096.f);
}

// ---------- kE: bn3 (redundant per-block batch stats) + all heads ----------
__global__ __launch_bounds__(256) void kE(
    const float* __restrict__ m, const float* __restrict__ g3, const float* __restrict__ b3,
    const float* __restrict__ agent, const float* __restrict__ action,
    const float* __restrict__ fc1w, const float* __restrict__ fc1b,
    const float* __restrict__ lnmig, const float* __restrict__ lnmib,
    const float* __restrict__ miw1, const float* __restrict__ miw2,
    const float* __restrict__ embc, const float* __restrict__ embe,
    const float* __restrict__ embnc, const float* __restrict__ embns,
    const float* __restrict__ embp,
    const float* __restrict__ lncag, const float* __restrict__ lncab,
    const float* __restrict__ caw1, const float* __restrict__ cab1,
    const float* __restrict__ caw2, const float* __restrict__ cab2,
    const float* __restrict__ lncg, const float* __restrict__ lncb,
    const float* __restrict__ cw,
    const float* __restrict__ lndg, const float* __restrict__ lndb,
    const float* __restrict__ dw1, const float* __restrict__ dw2,
    float* __restrict__ out) {
    __shared__ float red[4][128];
    __shared__ float xsh[128];
    __shared__ float lnv[28], lnca[24], lnsc[56], h1[100], h2[100], h3[50], cat[60];
    int b = blockIdx.x, tid = threadIdx.x;
    // bn3 batch stats (each block redundantly; m is 128KB, L2-hot)
    {
        int g = tid & 127, half = tid >> 7;
        float s = 0.f, s2 = 0.f;
        for (int i = 0; i < 128; ++i) {
            float v = m[(half * 128 + i) * 128 + g];
            s += v; s2 = fmaf(v, v, s2);
        }
        red[half * 2 + 0][g] = s;
        red[half * 2 + 1][g] = s2;
    }
    __syncthreads();
    if (tid < 128) {
        float s = red[0][tid] + red[2][tid], s2 = red[1][tid] + red[3][tid];
        float mean = s / 256.f, var = s2 / 256.f - mean * mean;
        float a = g3[tid] * rsqrtf(var + EPSF);
        float bb = b3[tid] - mean * a;
        xsh[tid] = fmaxf(0.f, fmaf(a, m[b * 128 + tid], bb));
    }
    // phase B: three LayerNorms, one per wave
    int l = tid & 63, w = tid >> 6;
    if (w == 0) {  // agent LN(28)
        float av = (l < 28) ? agent[b * 28 + l] : 0.f;
        float s = wave_sum(av), s2 = wave_sum(av * av);
        s = __shfl(s, 0); s2 = __shfl(s2, 0);
        float mean = s / 28.f, var = s2 / 28.f - mean * mean;
        float rs = rsqrtf(var + EPSF);
        if (l < 28) lnv[l] = (av - mean) * rs * lnmig[l] + lnmib[l];
    } else if (w == 1) {  // actions build + LN(24)
        const float* ab = action + b * 15;
        float actv = 0.f;
        if (l < 24) {
            if (l < 4)       actv = ab[l];
            else if (l < 7)  { int ix = (int)ab[4];  actv = embc[ix * 3 + (l - 4)]; }
            else if (l < 10) { int ix = (int)ab[5];  actv = embe[ix * 3 + (l - 7)]; }
            else if (l < 13) actv = ab[l - 4];
            else if (l < 16) { int ix = (int)ab[9];  actv = embnc[ix * 3 + (l - 13)]; }
            else if (l < 18) { int ix = (int)ab[10]; actv = embns[ix * 2 + (l - 16)]; }
            else if (l < 21) { int ix = (int)ab[11]; actv = embp[ix * 3 + (l - 18)]; }
            else             actv = ab[l - 9];
        }
        float s = wave_sum(actv), s2 = wave_sum(actv * actv);
        s = __shfl(s, 0); s2 = __shfl(s2, 0);
        float mean = s / 24.f, var = s2 / 24.f - mean * mean;
        float rs = rsqrtf(var + EPSF);
        if (l < 24) lnca[l] = (actv - mean) * rs * lncag[l] + lncab[l];
    } else if (w == 2) {  // dist LN(56): sc = [zeros(28), agent]
        float g1v = (l < 56) ? agent[b * 28 + (l < 28 ? l : l - 28)] : 0.f;
        float av = (l < 28) ? g1v : 0.f;
        float s = wave_sum(av), s2 = wave_sum(av * av);
        s = __shfl(s, 0); s2 = __shfl(s2, 0);
        float mean = s / 56.f, var = s2 / 56.f - mean * mean;
        float rs = rsqrtf(var + EPSF);
        if (l < 56) {
            float vv = (l < 28) ? 0.f : g1v;
            lnsc[l] = (vv - mean) * rs * lndg[l] + lndb[l];
        }
    }
    __syncthreads();
    // phase C: first-layer neurons, thread-parallel
    if (tid < 100) {
        float a = 0.f;
        for (int i = 0; i < 28; ++i) a = fmaf(miw1[tid * 28 + i], lnv[i], a);
        h1[tid] = fmaxf(0.f, a);
    } else if (tid < 200) {
        int j = tid - 100;
        float a = cab1[j];
        for (int i = 0; i < 24; ++i) a = fmaf(caw1[j * 24 + i], lnca[i], a);
        h2[j] = fmaxf(0.f, a);
    } else if (tid < 250) {
        int j = tid - 200;
        float a = 0.f;
        for (int i = 0; i < 56; ++i) a = fmaf(dw1[j * 56 + i], lnsc[i], a);
        h3[j] = tanhf(a);
    }
    __syncthreads();
    // phase D: second layers + dist output
    if (tid < 20) {
        float a = 0.f;
        for (int i = 0; i < 100; ++i) a = fmaf(miw2[tid * 100 + i], h1[i], a);
        cat[20 + tid] = fmaxf(0.f, a);
    } else if (tid >= 64 && tid < 84) {
        int j = tid - 64;
        float a = cab2[j];
        for (int i = 0; i < 100; ++i) a = fmaf(caw2[j * 100 + i], h2[i], a);
        cat[40 + j] = fmaxf(0.f, a);
    } else if (tid >= 128 && tid < 148) {
        int j = tid - 128;
        float a = fc1b[j];
        for (int i = 0; i < 128; ++i) a = fmaf(fc1w[j * 128 + i], xsh[i], a);
        cat[j] = fmaxf(0.f, a);
    } else if (tid >= 192) {
        int l3 = tid - 192;
        float dt = (l3 < 50) ? dw2[l3] * h3[l3] : 0.f;
        dt = wave_sum(dt);
        if (l3 == 0) out[256 + b] = tanhf(dt);
    }
    __syncthreads();
    // phase E: combined head LN(60) -> dot -> tanh (wave 0)
    if (w == 0) {
        float cv = (l < 60) ? cat[l] : 0.f;
        float ss = wave_sum(cv), ss2 = wave_sum(cv * cv);
        ss = __shfl(ss, 0); ss2 = __shfl(ss2, 0);
        float mean60 = ss / 60.f, var60 = ss2 / 60.f - mean60 * mean60;
        float rs60 = rsqrtf(var60 + EPSF);
        float term = (l < 60) ? cw[l] * ((cv - mean60) * rs60 * lncg[l] + lncb[l]) : 0.f;
        term = wave_sum(term);
        if (l == 0) out[b] = tanhf(term);
    }
}

extern "C" void kernel_launch(void* const* d_in, const int* in_sizes, int n_in,
                              void* d_out, int out_size, void* d_ws, size_t ws_size,
                              hipStream_t stream) {
    (void)in_sizes; (void)n_in; (void)out_size; (void)ws_size;
    const float* agent  = (const float*)d_in[0];
    const float* world  = (const float*)d_in[1];
    const float* action = (const float*)d_in[2];
    const float* bn1_g  = (const float*)d_in[3];
    const float* bn1_b  = (const float*)d_in[4];
    const float* conv1w = (const float*)d_in[5];
    const float* bn2_g  = (const float*)d_in[6];
    const float* bn2_b  = (const float*)d_in[7];
    const float* conv2w = (const float*)d_in[8];
    const float* bn3_g  = (const float*)d_in[9];
    const float* bn3_b  = (const float*)d_in[10];
    const float* fc1w   = (const float*)d_in[11];
    const float* fc1b   = (const float*)d_in[12];
    const float* lnmig  = (const float*)d_in[13];
    const float* lnmib  = (const float*)d_in[14];
    const float* miw1   = (const float*)d_in[15];
    const float* miw2   = (const float*)d_in[16];
    const float* embc   = (const float*)d_in[17];
    const float* embe   = (const float*)d_in[18];
    const float* embnc  = (const float*)d_in[19];
    const float* embns  = (const float*)d_in[20];
    const float* embp   = (const float*)d_in[21];
    const float* lncag  = (const float*)d_in[22];
    const float* lncab  = (const float*)d_in[23];
    const float* caw1   = (const float*)d_in[24];
    const float* cab1   = (const float*)d_in[25];
    const float* caw2   = (const float*)d_in[26];
    const float* cab2   = (const float*)d_in[27];
    const float* lncg   = (const float*)d_in[28];
    const float* lncb   = (const float*)d_in[29];
    const float* cw     = (const float*)d_in[30];
    const float* lndg   = (const float*)d_in[31];
    const float* lndb   = (const float*)d_in[32];
    const float* dw1    = (const float*)d_in[33];
    const float* dw2    = (const float*)d_in[34];
    float* out = (float*)d_out;
    float* ws = (float*)d_ws;

    hipLaunchKernelGGL(kA, dim3(256), dim3(256), 0, stream,
                       world, conv2w, ws + OFF_RED1, ws + OFF_W2E);
    hipLaunchKernelGGL(kB, dim3(256), dim3(256), 0, stream,
                       world, ws + OFF_RED1, bn1_g, bn1_b, ws + OFF_RED2, ws + OFF_A1B1);
    hipLaunchKernelGGL(kC, dim3(256), dim3(512), 0, stream,
                       world, ws + OFF_RED2, conv1w, bn2_g, bn2_b, ws + OFF_A1B1,
                       ws + OFF_W2E, ws + OFF_M);
    hipLaunchKernelGGL(kE, dim3(256), dim3(256), 0, stream,
                       ws + OFF_M, bn3_g, bn3_b, agent, action, fc1w, fc1b,
                       lnmig, lnmib, miw1, miw2,
                       embc, embe, embnc, embns, embp,
                       lncag, lncab, caw1, cab1, caw2, cab2,
                       lncg, lncb, cw, lndg, lndb, dw1, dw2, out);
}

// Round 3
// 187.342 us; speedup vs baseline: 1.2031x; 1.0668x over previous
//
#include <hip/hip_runtime.h>
#include <math.h>

#define EPSF 1e-5f

// B=256, C=3, H=W=64 (HW=4096), G=128
// ws layout (float offsets)
constexpr int OFF_RED1 = 0;        // 192*2  bn1 partials (sum,sumsq)
constexpr int OFF_A1B1 = 384;      // 6      folded bn1 affine a[3],b[3] (written by kB blk0)
constexpr int OFF_RED2 = 512;      // 256*9  t-moment partials
constexpr int OFF_W2E  = 4096;     // 128*128*9 effective conv2 weights
constexpr int OFF_M    = OFF_W2E + 128 * 128 * 9;  // 256*128 pooled conv2 output

__device__ __forceinline__ float wave_sum(float v) {
    #pragma unroll
    for (int off = 32; off > 0; off >>= 1) v += __shfl_down(v, off);
    return v;
}

// ---------- kA: bn1 partial stats (blocks 0..191) + effective conv2 weights (192..255) ----------
__global__ __launch_bounds__(256) void kA(const float* __restrict__ x,
                                          const float* __restrict__ w2,
                                          float* __restrict__ red1,
                                          float* __restrict__ w2e) {
    int blk = blockIdx.x, tid = threadIdx.x;
    if (blk < 192) {
        int c = blk % 3, seg = blk / 3;  // 64 segs x 4 b
        float s = 0.f, s2 = 0.f;
        for (int bb = 0; bb < 4; ++bb) {
            int b = seg * 4 + bb;
            const float4* p = (const float4*)(x + (size_t)(b * 3 + c) * 4096);
            for (int i = tid; i < 1024; i += 256) {
                float4 v = p[i];
                s += v.x + v.y + v.z + v.w;
                s2 = fmaf(v.x, v.x, s2); s2 = fmaf(v.y, v.y, s2);
                s2 = fmaf(v.z, v.z, s2); s2 = fmaf(v.w, v.w, s2);
            }
        }
        __shared__ float ls[4], ls2[4];
        float ws_ = wave_sum(s), ws2_ = wave_sum(s2);
        if ((tid & 63) == 0) { ls[tid >> 6] = ws_; ls2[tid >> 6] = ws2_; }
        __syncthreads();
        if (tid == 0) {
            red1[blk * 2 + 0] = ls[0] + ls[1] + ls[2] + ls[3];
            red1[blk * 2 + 1] = ls2[0] + ls2[1] + ls2[2] + ls2[3];
        }
    } else {
        // effective conv2 weights: feature order S,R0,R63,C0,C63,u00,u0_63,u63_0,u63_63
        int idx = (blk - 192) * 256 + tid;  // 16384 (g,g') pairs
        int g = idx >> 7, gp = idx & 127;
        const float* wp = w2 + (size_t)(g * 128 + gp) * 9;  // [ky][kx]
        float v0 = wp[0], v1 = wp[1], v2 = wp[2], v3 = wp[3], v4 = wp[4],
              v5 = wp[5], v6 = wp[6], v7 = wp[7], v8 = wp[8];
        float c[9];
        c[0] = ((v0 + v1) + (v2 + v3)) + ((v4 + v5) + (v6 + v7)) + v8;
        c[1] = -(v6 + v7 + v8);
        c[2] = -(v0 + v1 + v2);
        c[3] = -(v2 + v5 + v8);
        c[4] = -(v0 + v3 + v6);
        c[5] = v8; c[6] = v6; c[7] = v2; c[8] = v0;
        #pragma unroll
        for (int k = 0; k < 9; ++k) {
            int jj = gp * 9 + k;                                     // 0..1151
            w2e[(size_t)(jj >> 2) * 512 + g * 4 + (jj & 3)] = c[k];  // [jblk][g][4]
        }
    }
}

// ---------- kB: in-block bn1 finalize + per-b 3x3 second moments of t = relu(bn1(x)) ----------
__global__ __launch_bounds__(256) void kB(const float* __restrict__ x,
                                          const float* __restrict__ red1,
                                          const float* __restrict__ g1,
                                          const float* __restrict__ b1,
                                          float* __restrict__ red2,
                                          float* __restrict__ a1b1) {
    __shared__ float ab[6];
    int b = blockIdx.x, tid = threadIdx.x;
    if (tid < 3) {
        float s = 0.f, s2 = 0.f;
        for (int seg = 0; seg < 64; ++seg) {
            s  += red1[(seg * 3 + tid) * 2 + 0];
            s2 += red1[(seg * 3 + tid) * 2 + 1];
        }
        float n = 256.f * 4096.f;
        float mean = s / n, var = s2 / n - mean * mean;
        float a = g1[tid] * rsqrtf(var + EPSF);
        ab[tid] = a; ab[3 + tid] = b1[tid] - mean * a;
        if (b == 0) { a1b1[tid] = a; a1b1[3 + tid] = ab[3 + tid]; }
    }
    __syncthreads();
    float A0 = ab[0], A1 = ab[1], A2 = ab[2];
    float B0 = ab[3], B1 = ab[4], B2 = ab[5];
    float acc[9] = {0, 0, 0, 0, 0, 0, 0, 0, 0};
    const float4* p0 = (const float4*)(x + (size_t)(b * 3 + 0) * 4096);
    const float4* p1 = (const float4*)(x + (size_t)(b * 3 + 1) * 4096);
    const float4* p2 = (const float4*)(x + (size_t)(b * 3 + 2) * 4096);
    for (int i = tid; i < 1024; i += 256) {
        float4 v0 = p0[i], v1 = p1[i], v2 = p2[i];
        #define MOM(e) { \
            float t0 = fmaxf(0.f, fmaf(A0, v0.e, B0)); \
            float t1 = fmaxf(0.f, fmaf(A1, v1.e, B1)); \
            float t2 = fmaxf(0.f, fmaf(A2, v2.e, B2)); \
            acc[0] += t0; acc[1] += t1; acc[2] += t2; \
            acc[3] = fmaf(t0, t0, acc[3]); acc[4] = fmaf(t0, t1, acc[4]); \
            acc[5] = fmaf(t0, t2, acc[5]); acc[6] = fmaf(t1, t1, acc[6]); \
            acc[7] = fmaf(t1, t2, acc[7]); acc[8] = fmaf(t2, t2, acc[8]); }
        MOM(x) MOM(y) MOM(z) MOM(w)
        #undef MOM
    }
    __shared__ float lw[4][9];
    #pragma unroll
    for (int k = 0; k < 9; ++k) {
        float v = wave_sum(acc[k]);
        if ((tid & 63) == 0) lw[tid >> 6][k] = v;
    }
    __syncthreads();
    if (tid == 0) {
        #pragma unroll
        for (int k = 0; k < 9; ++k)
            red2[b * 9 + k] = lw[0][k] + lw[1][k] + lw[2][k] + lw[3][k];
    }
}

// ---------- kC: bn2 fold + boundary features + contract -> m[b,:] ----------
// Hot loop computes ONLY the full-plane sum S (no conditionals). Row/col/corner
// features are a tiny post-pass (1 thread per (g,task), 64 u's each).
__global__ __launch_bounds__(512) void kC(const float* __restrict__ x,
                                          const float* __restrict__ red2,
                                          const float* __restrict__ w1,
                                          const float* __restrict__ g2,
                                          const float* __restrict__ b2,
                                          const float* __restrict__ a1b1,
                                          const float* __restrict__ w2e,
                                          float* __restrict__ m) {
    __shared__ __align__(16) float lds[12288];  // t planes; reused for S-reduce + contract partials
    __shared__ __align__(16) float Fsh[1152];
    __shared__ float wt[384], bt[128], momp[288], mom[9], ab[6];
    int b = blockIdx.x, tid = threadIdx.x;
    if (tid < 6) ab[tid] = a1b1[tid];
    if (tid < 288) {  // 32 segs x 9 moments, 8 rows each — independent loads
        int seg = tid / 9, k = tid - seg * 9;
        float s = 0.f;
        #pragma unroll
        for (int r = 0; r < 8; ++r) s += red2[(seg * 8 + r) * 9 + k];
        momp[tid] = s;
    }
    __syncthreads();
    if (tid < 9) {
        float s = 0.f;
        #pragma unroll
        for (int sg = 0; sg < 32; ++sg) s += momp[sg * 9 + tid];
        mom[tid] = s / (256.f * 4096.f);
    }
    // stage t planes (ab ready — barrier above)
    {
        float A0 = ab[0], A1 = ab[1], A2 = ab[2];
        float B0 = ab[3], B1 = ab[4], B2 = ab[5];
        const float4* xb = (const float4*)(x + (size_t)b * 3 * 4096);
        for (int i = tid; i < 3072; i += 512) {
            float4 v = xb[i];
            int c = i >> 10;
            float a = (c == 0) ? A0 : ((c == 1) ? A1 : A2);
            float bb = (c == 0) ? B0 : ((c == 1) ? B1 : B2);
            v.x = fmaxf(0.f, fmaf(a, v.x, bb));
            v.y = fmaxf(0.f, fmaf(a, v.y, bb));
            v.z = fmaxf(0.f, fmaf(a, v.z, bb));
            v.w = fmaxf(0.f, fmaf(a, v.w, bb));
            *(float4*)&lds[i << 2] = v;
        }
    }
    __syncthreads();
    if (tid < 128) {  // bn2 fold into conv1 weights
        int g = tid;
        float wa = w1[g * 3 + 0], wb = w1[g * 3 + 1], wc = w1[g * 3 + 2];
        float mean = wa * mom[0] + wb * mom[1] + wc * mom[2];
        float ey2 = wa * wa * mom[3] + wb * wb * mom[6] + wc * wc * mom[8]
                  + 2.f * (wa * wb * mom[4] + wa * wc * mom[5] + wb * wc * mom[7]);
        float var = ey2 - mean * mean;
        float a = g2[g] * rsqrtf(var + EPSF);
        wt[g * 3 + 0] = a * wa; wt[g * 3 + 1] = a * wb; wt[g * 3 + 2] = a * wc;
        bt[g] = b2[g] - mean * a;
    }
    __syncthreads();
    // ---- hot loop: full-plane S only ----
    int gl = tid & 31, q = tid >> 5;  // 16 chunks x 256 pixels; 4 g's per thread
    {
        float w0[4], w1v[4], w2v[4], bw[4], S[4] = {0, 0, 0, 0};
        #pragma unroll
        for (int j = 0; j < 4; ++j) {
            int g = gl + 32 * j;
            w0[j] = wt[g * 3 + 0]; w1v[j] = wt[g * 3 + 1];
            w2v[j] = wt[g * 3 + 2]; bw[j] = bt[g];
        }
        int base = q * 256;
        #pragma unroll 4
        for (int i = 0; i < 64; ++i) {
            int pp = base + i * 4;
            float4 t0 = *(const float4*)&lds[pp];
            float4 t1 = *(const float4*)&lds[4096 + pp];
            float4 t2 = *(const float4*)&lds[8192 + pp];
            #pragma unroll
            for (int j = 0; j < 4; ++j) {
                float u0 = fmaxf(0.f, fmaf(w0[j], t0.x, fmaf(w1v[j], t1.x, fmaf(w2v[j], t2.x, bw[j]))));
                float u1 = fmaxf(0.f, fmaf(w0[j], t0.y, fmaf(w1v[j], t1.y, fmaf(w2v[j], t2.y, bw[j]))));
                float u2 = fmaxf(0.f, fmaf(w0[j], t0.z, fmaf(w1v[j], t1.z, fmaf(w2v[j], t2.z, bw[j]))));
                float u3 = fmaxf(0.f, fmaf(w0[j], t0.w, fmaf(w1v[j], t1.w, fmaf(w2v[j], t2.w, bw[j]))));
                S[j] += (u0 + u1) + (u2 + u3);
            }
        }
        // ---- boundary post-pass: 128 g x 4 tasks, one thread each ----
        {
            int g = tid & 127, task = tid >> 7;
            float vw0 = wt[g * 3 + 0], vw1 = wt[g * 3 + 1], vw2 = wt[g * 3 + 2], vb = bt[g];
            float s = 0.f, first = 0.f, last = 0.f;
            int p0 = (task == 1) ? 63 * 64 : ((task == 3) ? 63 : 0);
            int stp = (task >= 2) ? 64 : 1;
            #pragma unroll 4
            for (int i = 0; i < 64; ++i) {
                int p = p0 + i * stp;
                float u = fmaxf(0.f, fmaf(vw0, lds[p], fmaf(vw1, lds[4096 + p], fmaf(vw2, lds[8192 + p], vb))));
                s += u;
                if (i == 0) first = u;
                if (i == 63) last = u;
            }
            Fsh[g * 9 + 1 + task] = s;          // R0,R63,C0,C63
            if (task == 0) { Fsh[g * 9 + 5] = first; Fsh[g * 9 + 6] = last; }   // u00, u0_63
            if (task == 1) { Fsh[g * 9 + 7] = first; Fsh[g * 9 + 8] = last; }   // u63_0, u63_63
        }
        __syncthreads();  // everyone done reading t planes
        // S-reduce across the 16 q-chunks: padded stride 17 -> conflict-free
        #pragma unroll
        for (int j = 0; j < 4; ++j) lds[(gl + 32 * j) * 17 + q] = S[j];
    }
    __syncthreads();
    if (tid < 128) {
        float s = 0.f;
        #pragma unroll
        for (int qq = 0; qq < 16; ++qq) s += lds[tid * 17 + qq];
        Fsh[tid * 9 + 0] = s;
    }
    __syncthreads();
    // contract: m[b,g] = (1/4096) * sum_j w2e[j][g] * Fsh[j], split over 4 j-chunks
    {
        int chunk = tid >> 7, g = tid & 127;
        float acc = 0.f;
        #pragma unroll 4
        for (int t = 0; t < 72; ++t) {
            int jb = chunk * 72 + t;
            float4 wv = *(const float4*)&w2e[(size_t)jb * 512 + g * 4];
            float4 fv = *(const float4*)&Fsh[jb * 4];
            acc = fmaf(wv.x, fv.x, fmaf(wv.y, fv.y, fmaf(wv.z, fv.z, fmaf(wv.w, fv.w, acc))));
        }
        __syncthreads();
        lds[chunk * 128 + g] = acc;
    }
    __syncthreads();
    if (tid < 128)
        m[b * 128 + tid] = (lds[tid] + lds[128 + tid] + lds[256 + tid] + lds[384 + tid]) * (1.f / 4096.f);
}

// ---------- kE: bn3 (redundant per-block batch stats) + all heads ----------
__global__ __launch_bounds__(256) void kE(
    const float* __restrict__ m, const float* __restrict__ g3, const float* __restrict__ b3,
    const float* __restrict__ agent, const float* __restrict__ action,
    const float* __restrict__ fc1w, const float* __restrict__ fc1b,
    const float* __restrict__ lnmig, const float* __restrict__ lnmib,
    const float* __restrict__ miw1, const float* __restrict__ miw2,
    const float* __restrict__ embc, const float* __restrict__ embe,
    const float* __restrict__ embnc, const float* __restrict__ embns,
    const float* __restrict__ embp,
    const float* __restrict__ lncag, const float* __restrict__ lncab,
    const float* __restrict__ caw1, const float* __restrict__ cab1,
    const float* __restrict__ caw2, const float* __restrict__ cab2,
    const float* __restrict__ lncg, const float* __restrict__ lncb,
    const float* __restrict__ cw,
    const float* __restrict__ lndg, const float* __restrict__ lndb,
    const float* __restrict__ dw1, const float* __restrict__ dw2,
    float* __restrict__ out) {
    __shared__ float red[4][128];
    __shared__ float xsh[128];
    __shared__ float lnv[28], lnca[24], lnsc[56], h1[100], h2[100], h3[50], cat[60];
    int b = blockIdx.x, tid = threadIdx.x;
    // bn3 batch stats (each block redundantly; m is 128KB, L2-hot)
    {
        int g = tid & 127, half = tid >> 7;
        float s = 0.f, s2 = 0.f;
        for (int i = 0; i < 128; ++i) {
            float v = m[(half * 128 + i) * 128 + g];
            s += v; s2 = fmaf(v, v, s2);
        }
        red[half * 2 + 0][g] = s;
        red[half * 2 + 1][g] = s2;
    }
    __syncthreads();
    if (tid < 128) {
        float s = red[0][tid] + red[2][tid], s2 = red[1][tid] + red[3][tid];
        float mean = s / 256.f, var = s2 / 256.f - mean * mean;
        float a = g3[tid] * rsqrtf(var + EPSF);
        float bb = b3[tid] - mean * a;
        xsh[tid] = fmaxf(0.f, fmaf(a, m[b * 128 + tid], bb));
    }
    // phase B: three LayerNorms, one per wave
    int l = tid & 63, w = tid >> 6;
    if (w == 0) {  // agent LN(28)
        float av = (l < 28) ? agent[b * 28 + l] : 0.f;
        float s = wave_sum(av), s2 = wave_sum(av * av);
        s = __shfl(s, 0); s2 = __shfl(s2, 0);
        float mean = s / 28.f, var = s2 / 28.f - mean * mean;
        float rs = rsqrtf(var + EPSF);
        if (l < 28) lnv[l] = (av - mean) * rs * lnmig[l] + lnmib[l];
    } else if (w == 1) {  // actions build + LN(24)
        const float* ab = action + b * 15;
        float actv = 0.f;
        if (l < 24) {
            if (l < 4)       actv = ab[l];
            else if (l < 7)  { int ix = (int)ab[4];  actv = embc[ix * 3 + (l - 4)]; }
            else if (l < 10) { int ix = (int)ab[5];  actv = embe[ix * 3 + (l - 7)]; }
            else if (l < 13) actv = ab[l - 4];
            else if (l < 16) { int ix = (int)ab[9];  actv = embnc[ix * 3 + (l - 13)]; }
            else if (l < 18) { int ix = (int)ab[10]; actv = embns[ix * 2 + (l - 16)]; }
            else if (l < 21) { int ix = (int)ab[11]; actv = embp[ix * 3 + (l - 18)]; }
            else             actv = ab[l - 9];
        }
        float s = wave_sum(actv), s2 = wave_sum(actv * actv);
        s = __shfl(s, 0); s2 = __shfl(s2, 0);
        float mean = s / 24.f, var = s2 / 24.f - mean * mean;
        float rs = rsqrtf(var + EPSF);
        if (l < 24) lnca[l] = (actv - mean) * rs * lncag[l] + lncab[l];
    } else if (w == 2) {  // dist LN(56): sc = [zeros(28), agent]
        float g1v = (l < 56) ? agent[b * 28 + (l < 28 ? l : l - 28)] : 0.f;
        float av = (l < 28) ? g1v : 0.f;
        float s = wave_sum(av), s2 = wave_sum(av * av);
        s = __shfl(s, 0); s2 = __shfl(s2, 0);
        float mean = s / 56.f, var = s2 / 56.f - mean * mean;
        float rs = rsqrtf(var + EPSF);
        if (l < 56) {
            float vv = (l < 28) ? 0.f : g1v;
            lnsc[l] = (vv - mean) * rs * lndg[l] + lndb[l];
        }
    }
    __syncthreads();
    // phase C: first-layer neurons, thread-parallel
    if (tid < 100) {
        float a = 0.f;
        for (int i = 0; i < 28; ++i) a = fmaf(miw1[tid * 28 + i], lnv[i], a);
        h1[tid] = fmaxf(0.f, a);
    } else if (tid < 200) {
        int j = tid - 100;
        float a = cab1[j];
        for (int i = 0; i < 24; ++i) a = fmaf(caw1[j * 24 + i], lnca[i], a);
        h2[j] = fmaxf(0.f, a);
    } else if (tid < 250) {
        int j = tid - 200;
        float a = 0.f;
        for (int i = 0; i < 56; ++i) a = fmaf(dw1[j * 56 + i], lnsc[i], a);
        h3[j] = tanhf(a);
    }
    __syncthreads();
    // phase D: second layers + dist output
    if (tid < 20) {
        float a = 0.f;
        for (int i = 0; i < 100; ++i) a = fmaf(miw2[tid * 100 + i], h1[i], a);
        cat[20 + tid] = fmaxf(0.f, a);
    } else if (tid >= 64 && tid < 84) {
        int j = tid - 64;
        float a = cab2[j];
        for (int i = 0; i < 100; ++i) a = fmaf(caw2[j * 100 + i], h2[i], a);
        cat[40 + j] = fmaxf(0.f, a);
    } else if (tid >= 128 && tid < 148) {
        int j = tid - 128;
        float a = fc1b[j];
        for (int i = 0; i < 128; ++i) a = fmaf(fc1w[j * 128 + i], xsh[i], a);
        cat[j] = fmaxf(0.f, a);
    } else if (tid >= 192) {
        int l3 = tid - 192;
        float dt = (l3 < 50) ? dw2[l3] * h3[l3] : 0.f;
        dt = wave_sum(dt);
        if (l3 == 0) out[256 + b] = tanhf(dt);
    }
    __syncthreads();
    // phase E: combined head LN(60) -> dot -> tanh (wave 0)
    if (w == 0) {
        float cv = (l < 60) ? cat[l] : 0.f;
        float ss = wave_sum(cv), ss2 = wave_sum(cv * cv);
        ss = __shfl(ss, 0); ss2 = __shfl(ss2, 0);
        float mean60 = ss / 60.f, var60 = ss2 / 60.f - mean60 * mean60;
        float rs60 = rsqrtf(var60 + EPSF);
        float term = (l < 60) ? cw[l] * ((cv - mean60) * rs60 * lncg[l] + lncb[l]) : 0.f;
        term = wave_sum(term);
        if (l == 0) out[b] = tanhf(term);
    }
}

extern "C" void kernel_launch(void* const* d_in, const int* in_sizes, int n_in,
                              void* d_out, int out_size, void* d_ws, size_t ws_size,
                              hipStream_t stream) {
    (void)in_sizes; (void)n_in; (void)out_size; (void)ws_size;
    const float* agent  = (const float*)d_in[0];
    const float* world  = (const float*)d_in[1];
    const float* action = (const float*)d_in[2];
    const float* bn1_g  = (const float*)d_in[3];
    const float* bn1_b  = (const float*)d_in[4];
    const float* conv1w = (const float*)d_in[5];
    const float* bn2_g  = (const float*)d_in[6];
    const float* bn2_b  = (const float*)d_in[7];
    const float* conv2w = (const float*)d_in[8];
    const float* bn3_g  = (const float*)d_in[9];
    const float* bn3_b  = (const float*)d_in[10];
    const float* fc1w   = (const float*)d_in[11];
    const float* fc1b   = (const float*)d_in[12];
    const float* lnmig  = (const float*)d_in[13];
    const float* lnmib  = (const float*)d_in[14];
    const float* miw1   = (const float*)d_in[15];
    const float* miw2   = (const float*)d_in[16];
    const float* embc   = (const float*)d_in[17];
    const float* embe   = (const float*)d_in[18];
    const float* embnc  = (const float*)d_in[19];
    const float* embns  = (const float*)d_in[20];
    const float* embp   = (const float*)d_in[21];
    const float* lncag  = (const float*)d_in[22];
    const float* lncab  = (const float*)d_in[23];
    const float* caw1   = (const float*)d_in[24];
    const float* cab1   = (const float*)d_in[25];
    const float* caw2   = (const float*)d_in[26];
    const float* cab2   = (const float*)d_in[27];
    const float* lncg   = (const float*)d_in[28];
    const float* lncb   = (const float*)d_in[29];
    const float* cw     = (const float*)d_in[30];
    const float* lndg   = (const float*)d_in[31];
    const float* lndb   = (const float*)d_in[32];
    const float* dw1    = (const float*)d_in[33];
    const float* dw2    = (const float*)d_in[34];
    float* out = (float*)d_out;
    float* ws = (float*)d_ws;

    hipLaunchKernelGGL(kA, dim3(256), dim3(256), 0, stream,
                       world, conv2w, ws + OFF_RED1, ws + OFF_W2E);
    hipLaunchKernelGGL(kB, dim3(256), dim3(256), 0, stream,
                       world, ws + OFF_RED1, bn1_g, bn1_b, ws + OFF_RED2, ws + OFF_A1B1);
    hipLaunchKernelGGL(kC, dim3(256), dim3(512), 0, stream,
                       world, ws + OFF_RED2, conv1w, bn2_g, bn2_b, ws + OFF_A1B1,
                       ws + OFF_W2E, ws + OFF_M);
    hipLaunchKernelGGL(kE, dim3(256), dim3(256), 0, stream,
                       ws + OFF_M, bn3_g, bn3_b, agent, action, fc1w, fc1b,
                       lnmig, lnmib, miw1, miw2,
                       embc, embe, embnc, embns, embp,
                       lncag, lncab, caw1, cab1, caw2, cab2,
                       lncg, lncb, cw, lndg, lndb, dw1, dw2, out);
}